// Round 5
// baseline (309.003 us; speedup 1.0000x reference)
//
#include <hip/hip_runtime.h>
#include <hip/hip_bf16.h>
#include <stdint.h>

#define N_TOK 8192
#define DDIM 1024
#define FDIM 4096
#define NEXP 8

typedef __attribute__((ext_vector_type(8))) short short8;
typedef __attribute__((ext_vector_type(4))) float f32x4;

__device__ __forceinline__ ushort f2bf(float f) {
  uint32_t u = __float_as_uint(f);
  u += 0x7FFF + ((u >> 16) & 1);   // RNE
  return (ushort)(u >> 16);
}

__device__ __forceinline__ void gload16(const void* g, void* l) {
  __builtin_amdgcn_global_load_lds((const __attribute__((address_space(1))) void*)g,
                                   (__attribute__((address_space(3))) void*)l, 16, 0, 0);
}

// ---------- fused cast f32 -> bf16 for both weight matrices ----------
__global__ __launch_bounds__(256) void cast2_kernel(const float* __restrict__ wi,
                                                    const float* __restrict__ wo,
                                                    ushort* __restrict__ wib,
                                                    ushort* __restrict__ wob) {
  const int N1 = FDIM * DDIM / 4;            // 1048576 float4 units each
  int i = blockIdx.x * 256 + threadIdx.x;
  const float* src;
  ushort* dst;
  int j;
  if (i < N1) { src = wi; dst = wib; j = i; }
  else        { src = wo; dst = wob; j = i - N1; }
  float4 v = reinterpret_cast<const float4*>(src)[j];
  ushort4 o;
  o.x = f2bf(v.x); o.y = f2bf(v.y); o.z = f2bf(v.z); o.w = f2bf(v.w);
  reinterpret_cast<ushort4*>(dst)[j] = o;
}

// ---------- router (proven) ----------
__global__ __launch_bounds__(256) void router_kernel(
    const float* __restrict__ x, const float* __restrict__ gW, const float* __restrict__ gb,
    const float* __restrict__ lA, int* __restrict__ top1, float* __restrict__ coeff,
    ushort* __restrict__ xb) {
  const int lane = threadIdx.x & 63;
  const int wid = threadIdx.x >> 6;
  const int tok = blockIdx.x * 4 + wid;
  const float* xp = x + (size_t)tok * DDIM;
  float4 xv[4];
#pragma unroll
  for (int i = 0; i < 4; ++i)
    xv[i] = *reinterpret_cast<const float4*>(xp + i * 256 + lane * 4);
#pragma unroll
  for (int i = 0; i < 4; ++i) {
    ushort4 o;
    o.x = f2bf(xv[i].x); o.y = f2bf(xv[i].y); o.z = f2bf(xv[i].z); o.w = f2bf(xv[i].w);
    *reinterpret_cast<ushort4*>(xb + (size_t)tok * DDIM + i * 256 + lane * 4) = o;
  }
  double lg[NEXP];
#pragma unroll
  for (int e = 0; e < NEXP; ++e) {
    const float* gp = gW + e * DDIM;
    double s = 0.0;
#pragma unroll
    for (int i = 0; i < 4; ++i) {
      float4 g = *reinterpret_cast<const float4*>(gp + i * 256 + lane * 4);
      s += (double)xv[i].x * g.x + (double)xv[i].y * g.y +
           (double)xv[i].z * g.z + (double)xv[i].w * g.w;
    }
    lg[e] = s;
  }
#pragma unroll
  for (int e = 0; e < NEXP; ++e)
    for (int off = 32; off > 0; off >>= 1) lg[e] += __shfl_xor(lg[e], off);
  int best = 0;
  double bv = lg[0] + (double)gb[0];
#pragma unroll
  for (int e = 1; e < NEXP; ++e) {
    double v = lg[e] + (double)gb[e];
    if (v > bv) { bv = v; best = e; }
  }
  float c[4];
#pragma unroll
  for (int r = 0; r < 4; ++r) {
    const float* ap = lA + ((size_t)best * 4 + r) * DDIM;
    float s = 0.f;
#pragma unroll
    for (int i = 0; i < 4; ++i) {
      float4 a = *reinterpret_cast<const float4*>(ap + i * 256 + lane * 4);
      s = fmaf(xv[i].x, a.x, s); s = fmaf(xv[i].y, a.y, s);
      s = fmaf(xv[i].z, a.z, s); s = fmaf(xv[i].w, a.w, s);
    }
    for (int off = 32; off > 0; off >>= 1) s += __shfl_xor(s, off);
    c[r] = s;
  }
  if (lane == 0) {
    top1[tok] = best;
    float4 cc; cc.x = c[0]; cc.y = c[1]; cc.z = c[2]; cc.w = c[3];
    *reinterpret_cast<float4*>(coeff + tok * 4) = cc;
  }
}

// =====================================================================
// GEMM1: inter = relu(xb[8192,1024] @ wiWb[4096,1024]^T + wi_b + lora)
// m97 structure: 128x128 tile, BK=32, 256 thr (4 waves 2x2, wave 64x64),
// single-buffer chunk-major LDS (zero-conflict), global_load_lds w16,
// __syncthreads loop (compiler-scheduled), multi-block/CU occupancy.
// LDS: staging 16KB; epilogue overlay (lora/coeff/top1) 18.5KB -> 19KB decl.
// =====================================================================
__global__ __launch_bounds__(256, 4) void gemm1_kernel(
    const ushort* __restrict__ A, const ushort* __restrict__ B,
    const float* __restrict__ bias, const int* __restrict__ top1,
    const float4* __restrict__ coeff, const float4* __restrict__ loraB,
    ushort* __restrict__ C) {
  __shared__ __align__(16) ushort lds[9472];     // 18.94 KB (max of 16KB staging / 18.5KB overlay)
  const int tid = threadIdx.x;
  const int lane = tid & 63;
  const int wid = tid >> 6;
  const int wr = wid >> 1, wc = wid & 1;         // 2x2 waves, each 64x64

  // XCD swizzle: nwg = 2048 (64 mblk x 32 nblk), %8==0 -> bijective
  int bid = blockIdx.x;
  int swz = (bid & 7) * 256 + (bid >> 3);
  const int brow = swz >> 5, bcol = swz & 31;

  // staging: thread (rs, ch) writes chunks ch and ch+2 of its row
  const int rs = tid & 127, ch = tid >> 7;
  const ushort* gA = A + (size_t)(brow * 128 + rs) * DDIM + ch * 8;
  const ushort* gB = B + (size_t)(bcol * 128 + rs) * DDIM + ch * 8;
  ushort* const dstA = lds + tid * 8;            // [chunk][row][8]: ch*1024 + rs*8
  ushort* const dstB = lds + 4096 + tid * 8;

  // ds_read offsets: group g = lane>>4 reads chunk g, rows contiguous (256B/group)
  const int g = lane >> 4, rlo = lane & 15;
  const int aoff = g * 1024 + (wr * 64 + rlo) * 8;
  const int boff = 4096 + g * 1024 + (wc * 64 + rlo) * 8;

  f32x4 acc[4][4] = {};

  for (int t = 0; t < DDIM / 32; ++t) {
    const int k0 = t * 32;
    gload16(gA + k0, dstA);  gload16(gA + k0 + 16, dstA + 2048);
    gload16(gB + k0, dstB);  gload16(gB + k0 + 16, dstB + 2048);
    __syncthreads();
    short8 a[4], b[4];
#pragma unroll
    for (int fm = 0; fm < 4; ++fm)
      a[fm] = *reinterpret_cast<const short8*>(lds + aoff + fm * 128);
#pragma unroll
    for (int fn = 0; fn < 4; ++fn)
      b[fn] = *reinterpret_cast<const short8*>(lds + boff + fn * 128);
#pragma unroll
    for (int fn = 0; fn < 4; ++fn)
#pragma unroll
      for (int fm = 0; fm < 4; ++fm)
        acc[fm][fn] = __builtin_amdgcn_mfma_f32_16x16x32_bf16(a[fm], b[fn], acc[fm][fn], 0, 0, 0);
    __syncthreads();
  }

  // ---- epilogue: LDS-staged lora/coeff/top1 (proven round-2), fused relu ----
  float4* lora_s  = (float4*)lds;                    // [8][128] = 16 KB
  float4* coeff_s = (float4*)((char*)lds + 16384);   // [128]    =  2 KB
  int*    top1_s  = (int*)  ((char*)lds + 18432);    // [128]    = 512 B
#pragma unroll
  for (int i = 0; i < 4; ++i) {
    int idx = tid + i * 256;                         // 1024 = 8 experts x 128 cols
    lora_s[idx] = loraB[(size_t)(idx >> 7) * FDIM + bcol * 128 + (idx & 127)];
  }
  if (tid < 128) {
    coeff_s[tid] = coeff[brow * 128 + tid];
    top1_s[tid]  = top1[brow * 128 + tid];
  }
  __syncthreads();

  const int ccb = wc * 64 + (lane & 15);
  float bias4[4];
#pragma unroll
  for (int fn = 0; fn < 4; ++fn) bias4[fn] = bias[bcol * 128 + ccb + fn * 16];
#pragma unroll
  for (int fm = 0; fm < 4; ++fm) {
#pragma unroll
    for (int q = 0; q < 4; ++q) {
      const int tl = wr * 64 + fm * 16 + ((lane >> 4) << 2) + q;
      const int e = top1_s[tl];
      const float4 cf = coeff_s[tl];
      ushort* crow = C + (size_t)(brow * 128 + tl) * FDIM + bcol * 128;
#pragma unroll
      for (int fn = 0; fn < 4; ++fn) {
        const int cc = ccb + fn * 16;
        const float4 l4 = lora_s[e * 128 + cc];
        float v = acc[fm][fn][q] + bias4[fn] +
                  cf.x * l4.x + cf.y * l4.y + cf.z * l4.z + cf.w * l4.w;
        crow[cc] = f2bf(fmaxf(v, 0.f));
      }
    }
  }
}

// =====================================================================
// GEMM2: out = inter[8192,4096] @ woWb[1024,4096]^T + wo_b   (f32 out)
// Same m97 structure, K=4096 (128 k-steps). 512 blocks (64x8), 16KB LDS.
// =====================================================================
__global__ __launch_bounds__(256, 4) void gemm2_kernel(
    const ushort* __restrict__ A, const ushort* __restrict__ B,
    const float* __restrict__ bias, float* __restrict__ C) {
  __shared__ __align__(16) ushort lds[8192];     // 16 KB
  const int tid = threadIdx.x;
  const int lane = tid & 63;
  const int wid = tid >> 6;
  const int wr = wid >> 1, wc = wid & 1;

  int bid = blockIdx.x;                          // nwg = 512 (64 mblk x 8 nblk)
  int swz = (bid & 7) * 64 + (bid >> 3);
  const int brow = swz >> 3, bcol = swz & 7;

  const int rs = tid & 127, ch = tid >> 7;
  const ushort* gA = A + (size_t)(brow * 128 + rs) * FDIM + ch * 8;
  const ushort* gB = B + (size_t)(bcol * 128 + rs) * FDIM + ch * 8;
  ushort* const dstA = lds + tid * 8;
  ushort* const dstB = lds + 4096 + tid * 8;

  const int g = lane >> 4, rlo = lane & 15;
  const int aoff = g * 1024 + (wr * 64 + rlo) * 8;
  const int boff = 4096 + g * 1024 + (wc * 64 + rlo) * 8;

  f32x4 acc[4][4] = {};

  for (int t = 0; t < FDIM / 32; ++t) {
    const int k0 = t * 32;
    gload16(gA + k0, dstA);  gload16(gA + k0 + 16, dstA + 2048);
    gload16(gB + k0, dstB);  gload16(gB + k0 + 16, dstB + 2048);
    __syncthreads();
    short8 a[4], b[4];
#pragma unroll
    for (int fm = 0; fm < 4; ++fm)
      a[fm] = *reinterpret_cast<const short8*>(lds + aoff + fm * 128);
#pragma unroll
    for (int fn = 0; fn < 4; ++fn)
      b[fn] = *reinterpret_cast<const short8*>(lds + boff + fn * 128);
#pragma unroll
    for (int fn = 0; fn < 4; ++fn)
#pragma unroll
      for (int fm = 0; fm < 4; ++fm)
        acc[fm][fn] = __builtin_amdgcn_mfma_f32_16x16x32_bf16(a[fm], b[fn], acc[fm][fn], 0, 0, 0);
    __syncthreads();
  }

  const int ccb = wc * 64 + (lane & 15);
  float bias4[4];
#pragma unroll
  for (int fn = 0; fn < 4; ++fn) bias4[fn] = bias[bcol * 128 + ccb + fn * 16];
#pragma unroll
  for (int fm = 0; fm < 4; ++fm) {
#pragma unroll
    for (int q = 0; q < 4; ++q) {
      const int tl = wr * 64 + fm * 16 + ((lane >> 4) << 2) + q;
      float* crow = C + (size_t)(brow * 128 + tl) * DDIM + bcol * 128;
#pragma unroll
      for (int fn = 0; fn < 4; ++fn)
        crow[ccb + fn * 16] = acc[fm][fn][q] + bias4[fn];
    }
  }
}

extern "C" void kernel_launch(void* const* d_in, const int* in_sizes, int n_in,
                              void* d_out, int out_size, void* d_ws, size_t ws_size,
                              hipStream_t stream) {
  const float* x      = (const float*)d_in[0];
  const float* gate_W = (const float*)d_in[1];
  const float* gate_b = (const float*)d_in[2];
  const float* wi_W   = (const float*)d_in[3];
  const float* wi_b   = (const float*)d_in[4];
  const float* wo_W   = (const float*)d_in[5];
  const float* wo_b   = (const float*)d_in[6];
  const float* lora_A = (const float*)d_in[7];
  const float* lora_B = (const float*)d_in[8];
  float* out = (float*)d_out;

  char* ws = (char*)d_ws;
  ushort* xb    = (ushort*)(ws);                       // 16.78 MB
  ushort* wiWb  = (ushort*)(ws + 16777216);            //  8.39 MB
  ushort* woWb  = (ushort*)(ws + 25165824);            //  8.39 MB
  ushort* inter = (ushort*)(ws + 33554432);            // 67.1  MB
  int*    top1  = (int*)   (ws + 100663296);           // 32 KB
  float*  coeff = (float*) (ws + 100696064);           // 128 KB

  cast2_kernel<<<8192, 256, 0, stream>>>(wi_W, wo_W, wiWb, woWb);
  router_kernel<<<N_TOK / 4, 256, 0, stream>>>(x, gate_W, gate_b, lora_A, top1, coeff, xb);
  gemm1_kernel<<<2048, 256, 0, stream>>>(
      xb, wiWb, wi_b, top1, (const float4*)coeff, (const float4*)lora_B, inter);
  gemm2_kernel<<<512, 256, 0, stream>>>(inter, woWb, wo_b, out);
}

// Round 6
// 271.952 us; speedup vs baseline: 1.1362x; 1.1362x over previous
//
#include <hip/hip_runtime.h>
#include <hip/hip_bf16.h>
#include <stdint.h>

#define N_TOK 8192
#define DDIM 1024
#define FDIM 4096
#define NEXP 8

typedef __attribute__((ext_vector_type(8))) short short8;
typedef __attribute__((ext_vector_type(4))) float f32x4;

#define SCHED_FENCE __builtin_amdgcn_sched_barrier(0)
#define CFENCE asm volatile("" ::: "memory")
#define HWBAR __builtin_amdgcn_s_barrier()

__device__ __forceinline__ ushort f2bf(float f) {
  uint32_t u = __float_as_uint(f);
  u += 0x7FFF + ((u >> 16) & 1);   // RNE
  return (ushort)(u >> 16);
}

__device__ __forceinline__ void gload16(const void* g, void* l) {
  __builtin_amdgcn_global_load_lds((const __attribute__((address_space(1))) void*)g,
                                   (__attribute__((address_space(3))) void*)l, 16, 0, 0);
}

// ---------- fused cast f32 -> bf16 for both weight matrices ----------
__global__ __launch_bounds__(256) void cast2_kernel(const float* __restrict__ wi,
                                                    const float* __restrict__ wo,
                                                    ushort* __restrict__ wib,
                                                    ushort* __restrict__ wob) {
  const int N1 = FDIM * DDIM / 4;
  int i = blockIdx.x * 256 + threadIdx.x;
  const float* src;
  ushort* dst;
  int j;
  if (i < N1) { src = wi; dst = wib; j = i; }
  else        { src = wo; dst = wob; j = i - N1; }
  float4 v = reinterpret_cast<const float4*>(src)[j];
  ushort4 o;
  o.x = f2bf(v.x); o.y = f2bf(v.y); o.z = f2bf(v.z); o.w = f2bf(v.w);
  reinterpret_cast<ushort4*>(dst)[j] = o;
}

// ---------- router (proven) ----------
__global__ __launch_bounds__(256) void router_kernel(
    const float* __restrict__ x, const float* __restrict__ gW, const float* __restrict__ gb,
    const float* __restrict__ lA, int* __restrict__ top1, float* __restrict__ coeff,
    ushort* __restrict__ xb) {
  const int lane = threadIdx.x & 63;
  const int wid = threadIdx.x >> 6;
  const int tok = blockIdx.x * 4 + wid;
  const float* xp = x + (size_t)tok * DDIM;
  float4 xv[4];
#pragma unroll
  for (int i = 0; i < 4; ++i)
    xv[i] = *reinterpret_cast<const float4*>(xp + i * 256 + lane * 4);
#pragma unroll
  for (int i = 0; i < 4; ++i) {
    ushort4 o;
    o.x = f2bf(xv[i].x); o.y = f2bf(xv[i].y); o.z = f2bf(xv[i].z); o.w = f2bf(xv[i].w);
    *reinterpret_cast<ushort4*>(xb + (size_t)tok * DDIM + i * 256 + lane * 4) = o;
  }
  double lg[NEXP];
#pragma unroll
  for (int e = 0; e < NEXP; ++e) {
    const float* gp = gW + e * DDIM;
    double s = 0.0;
#pragma unroll
    for (int i = 0; i < 4; ++i) {
      float4 g = *reinterpret_cast<const float4*>(gp + i * 256 + lane * 4);
      s += (double)xv[i].x * g.x + (double)xv[i].y * g.y +
           (double)xv[i].z * g.z + (double)xv[i].w * g.w;
    }
    lg[e] = s;
  }
#pragma unroll
  for (int e = 0; e < NEXP; ++e)
    for (int off = 32; off > 0; off >>= 1) lg[e] += __shfl_xor(lg[e], off);
  int best = 0;
  double bv = lg[0] + (double)gb[0];
#pragma unroll
  for (int e = 1; e < NEXP; ++e) {
    double v = lg[e] + (double)gb[e];
    if (v > bv) { bv = v; best = e; }
  }
  float c[4];
#pragma unroll
  for (int r = 0; r < 4; ++r) {
    const float* ap = lA + ((size_t)best * 4 + r) * DDIM;
    float s = 0.f;
#pragma unroll
    for (int i = 0; i < 4; ++i) {
      float4 a = *reinterpret_cast<const float4*>(ap + i * 256 + lane * 4);
      s = fmaf(xv[i].x, a.x, s); s = fmaf(xv[i].y, a.y, s);
      s = fmaf(xv[i].z, a.z, s); s = fmaf(xv[i].w, a.w, s);
    }
    for (int off = 32; off > 0; off >>= 1) s += __shfl_xor(s, off);
    c[r] = s;
  }
  if (lane == 0) {
    top1[tok] = best;
    float4 cc; cc.x = c[0]; cc.y = c[1]; cc.z = c[2]; cc.w = c[3];
    *reinterpret_cast<float4*>(coeff + tok * 4) = cc;
  }
}

// =====================================================================
// GEMM1 (round-2 proven structure, ~86us): 256x256 tile, BK=32, 8 waves
// (2Mx4N), 4-slot LDS ring, 2-tile lookahead, per-tile vmcnt(4).
// Swizzle FIXED: within an XCD consecutive blocks walk M (share B panel).
// =====================================================================
__global__ __launch_bounds__(512, 2) void gemm1_kernel(
    const ushort* __restrict__ A, const ushort* __restrict__ B,
    const float* __restrict__ bias, const int* __restrict__ top1,
    const float4* __restrict__ coeff, const float4* __restrict__ loraB,
    ushort* __restrict__ C) {
  __shared__ __align__(16) ushort lds[65536];     // 128 KiB
  const int tid = threadIdx.x;
  const int lane = tid & 63;
  const int wid = tid >> 6;
  const int wr = wid >> 2, wc = wid & 3;          // 2M x 4N waves

  // XCD swizzle, m-fastest within XCD (nwg=512, %8==0 -> bijective)
  int bid = blockIdx.x;
  int swz = (bid & 7) * 64 + (bid >> 3);
  const int brow = swz & 31;                      // 32 m-blocks (walk M)
  const int bcol = swz >> 5;                      // 16 n-blocks (B panel resident)

  const int NT = DDIM / 32;                       // 32 k-tiles

  const int rs = tid & 255, ch = tid >> 8;        // ch in {0,1}
  const ushort* gA0 = A + (size_t)(brow * 256 + rs) * DDIM + ch * 8;
  const ushort* gA1 = gA0 + 16;
  const ushort* gB0 = B + (size_t)(bcol * 256 + rs) * DDIM + ch * 8;
  const ushort* gB1 = gB0 + 16;
  ushort* const sdst = lds + tid * 8;

  const int cA = lane >> 4, rlo = lane & 15;
  const int aoff = ((cA << 8) + wr * 128 + rlo) * 8;          // + (h*4+fm)*128
  const int boff = 8192 + ((cA << 8) + wc * 64 + rlo) * 8;    // + fn*128

  f32x4 acc[8][4] = {};

  // prologue: stage tiles 0 (slot0) and 1 (slot1)
  gload16(gA0,      sdst);                 gload16(gA1,      sdst + 4096);
  gload16(gB0,      sdst + 8192);          gload16(gB1,      sdst + 12288);
  gload16(gA0 + 32, sdst + 16384);         gload16(gA1 + 32, sdst + 16384 + 4096);
  gload16(gB0 + 32, sdst + 16384 + 8192);  gload16(gB1 + 32, sdst + 16384 + 12288);
  asm volatile("s_waitcnt vmcnt(4)" ::: "memory");
  SCHED_FENCE; HWBAR; SCHED_FENCE;

#pragma unroll 1
  for (int t = 0; t < NT; ++t) {
    const ushort* sp = lds + (t & 3) * 16384;
    const int t2 = t + 2;
    ushort* s2 = sdst + (t2 & 3) * 16384;
    const int k2 = t2 * 32;
    short8 a0[4], b0[4];
    // ---- phase 0: read A(h=0) + B, stage A of tile t+2 ----
    CFENCE;
#pragma unroll
    for (int fm = 0; fm < 4; ++fm)
      a0[fm] = *reinterpret_cast<const short8*>(sp + aoff + fm * 128);
#pragma unroll
    for (int fn = 0; fn < 4; ++fn)
      b0[fn] = *reinterpret_cast<const short8*>(sp + boff + fn * 128);
    if (t2 < NT) { gload16(gA0 + k2, s2); gload16(gA1 + k2, s2 + 4096); }
    CFENCE; SCHED_FENCE; HWBAR; SCHED_FENCE;
    __builtin_amdgcn_s_setprio(1);
#pragma unroll
    for (int fn = 0; fn < 4; ++fn)
#pragma unroll
      for (int fm = 0; fm < 4; ++fm)
        acc[fm][fn] = __builtin_amdgcn_mfma_f32_16x16x32_bf16(a0[fm], b0[fn], acc[fm][fn], 0, 0, 0);
    __builtin_amdgcn_s_setprio(0);
    SCHED_FENCE; CFENCE; HWBAR; SCHED_FENCE;
    // ---- phase 1: read A(h=1), stage B of tile t+2, tile-end wait ----
    CFENCE;
#pragma unroll
    for (int fm = 0; fm < 4; ++fm)
      a0[fm] = *reinterpret_cast<const short8*>(sp + aoff + 512 + fm * 128);
    if (t2 < NT) { gload16(gB0 + k2, s2 + 8192); gload16(gB1 + k2, s2 + 12288); }
    CFENCE; SCHED_FENCE; HWBAR; SCHED_FENCE;
    __builtin_amdgcn_s_setprio(1);
#pragma unroll
    for (int fn = 0; fn < 4; ++fn)
#pragma unroll
      for (int fm = 0; fm < 4; ++fm)
        acc[4 + fm][fn] = __builtin_amdgcn_mfma_f32_16x16x32_bf16(a0[fm], b0[fn], acc[4 + fm][fn], 0, 0, 0);
    __builtin_amdgcn_s_setprio(0);
    SCHED_FENCE;
    if (t2 < NT) asm volatile("s_waitcnt vmcnt(4)" ::: "memory");
    else         asm volatile("s_waitcnt vmcnt(0)" ::: "memory");
    HWBAR; SCHED_FENCE;
  }

  // ---- epilogue: LDS-staged lora/coeff/top1, fused bias+lora+relu ----
  __syncthreads();
  char* lb = (char*)lds;
  float4* lora_s  = (float4*)lb;             // [8][256] = 32 KB
  float4* coeff_s = (float4*)(lb + 32768);   // [256]
  int*    top1_s  = (int*)  (lb + 36864);    // [256]
#pragma unroll
  for (int i = 0; i < 4; ++i) {
    int idx = tid + i * 512;
    lora_s[idx] = loraB[(size_t)(idx >> 8) * FDIM + bcol * 256 + (idx & 255)];
  }
  if (tid < 256) {
    coeff_s[tid] = coeff[brow * 256 + tid];
    top1_s[tid]  = top1[brow * 256 + tid];
  }
  __syncthreads();

  const int ccb = wc * 64 + (lane & 15);
  float bias4[4];
#pragma unroll
  for (int fn = 0; fn < 4; ++fn) bias4[fn] = bias[bcol * 256 + ccb + fn * 16];
#pragma unroll
  for (int fm = 0; fm < 8; ++fm) {
#pragma unroll
    for (int q = 0; q < 4; ++q) {
      const int tl = wr * 128 + fm * 16 + ((lane >> 4) << 2) + q;
      const int e = top1_s[tl];
      const float4 cf = coeff_s[tl];
      ushort* crow = C + (size_t)(brow * 256 + tl) * FDIM + bcol * 256;
#pragma unroll
      for (int fn = 0; fn < 4; ++fn) {
        const int cc = ccb + fn * 16;
        const float4 l4 = lora_s[e * 256 + cc];
        float v = acc[fm][fn][q] + bias4[fn] +
                  cf.x * l4.x + cf.y * l4.y + cf.z * l4.z + cf.w * l4.w;
        crow[cc] = f2bf(fmaxf(v, 0.f));
      }
    }
  }
}

// =====================================================================
// GEMM2 (round-1 proven regime + zero-conflict LDS): out = inter @ woWb^T + wo_b
// 128x128 tile, BK=32, 256 thr (2x2 waves of 64x64), single-buffer 16KB
// chunk-major LDS, compiler-scheduled __syncthreads, multi-block/CU.
// Swizzle: each XCD owns one output column (1MB B panel L2-resident).
// =====================================================================
__global__ __launch_bounds__(256) void gemm2_kernel(
    const ushort* __restrict__ A, const ushort* __restrict__ B,
    const float* __restrict__ bias, float* __restrict__ C) {
  __shared__ __align__(16) ushort lds[8192];     // 16 KB
  const int tid = threadIdx.x;
  const int lane = tid & 63;
  const int wid = tid >> 6;
  const int wr = wid >> 1, wc = wid & 1;

  const int bid = blockIdx.x;                    // nwg = 512 (64 m x 8 n)
  const int brow = bid >> 3;                     // walk M within XCD
  const int bcol = bid & 7;                      // XCD-pinned column

  const int rs = tid & 127, ch = tid >> 7;
  const ushort* gA = A + (size_t)(brow * 128 + rs) * FDIM + ch * 8;
  const ushort* gB = B + (size_t)(bcol * 128 + rs) * FDIM + ch * 8;
  ushort* const dstA = lds + tid * 8;            // [chunk][row][8]
  ushort* const dstB = lds + 4096 + tid * 8;

  const int g = lane >> 4, rlo = lane & 15;
  const int aoff = g * 1024 + (wr * 64 + rlo) * 8;
  const int boff = 4096 + g * 1024 + (wc * 64 + rlo) * 8;

  f32x4 acc[4][4] = {};

  for (int t = 0; t < FDIM / 32; ++t) {
    const int k0 = t * 32;
    gload16(gA + k0, dstA);  gload16(gA + k0 + 16, dstA + 2048);
    gload16(gB + k0, dstB);  gload16(gB + k0 + 16, dstB + 2048);
    __syncthreads();
    short8 a[4], b[4];
#pragma unroll
    for (int fm = 0; fm < 4; ++fm)
      a[fm] = *reinterpret_cast<const short8*>(lds + aoff + fm * 128);
#pragma unroll
    for (int fn = 0; fn < 4; ++fn)
      b[fn] = *reinterpret_cast<const short8*>(lds + boff + fn * 128);
#pragma unroll
    for (int fn = 0; fn < 4; ++fn)
#pragma unroll
      for (int fm = 0; fm < 4; ++fm)
        acc[fm][fn] = __builtin_amdgcn_mfma_f32_16x16x32_bf16(a[fm], b[fn], acc[fm][fn], 0, 0, 0);
    __syncthreads();
  }

  const int ccb = wc * 64 + (lane & 15);
  float bias4[4];
#pragma unroll
  for (int fn = 0; fn < 4; ++fn) bias4[fn] = bias[bcol * 128 + ccb + fn * 16];
#pragma unroll
  for (int fm = 0; fm < 4; ++fm) {
#pragma unroll
    for (int q = 0; q < 4; ++q) {
      const int tl = wr * 64 + fm * 16 + ((lane >> 4) << 2) + q;
      float* crow = C + (size_t)(brow * 128 + tl) * DDIM + bcol * 128;
#pragma unroll
      for (int fn = 0; fn < 4; ++fn)
        crow[ccb + fn * 16] = acc[fm][fn][q] + bias4[fn];
    }
  }
}

extern "C" void kernel_launch(void* const* d_in, const int* in_sizes, int n_in,
                              void* d_out, int out_size, void* d_ws, size_t ws_size,
                              hipStream_t stream) {
  const float* x      = (const float*)d_in[0];
  const float* gate_W = (const float*)d_in[1];
  const float* gate_b = (const float*)d_in[2];
  const float* wi_W   = (const float*)d_in[3];
  const float* wi_b   = (const float*)d_in[4];
  const float* wo_W   = (const float*)d_in[5];
  const float* wo_b   = (const float*)d_in[6];
  const float* lora_A = (const float*)d_in[7];
  const float* lora_B = (const float*)d_in[8];
  float* out = (float*)d_out;

  char* ws = (char*)d_ws;
  ushort* xb    = (ushort*)(ws);                       // 16.78 MB
  ushort* wiWb  = (ushort*)(ws + 16777216);            //  8.39 MB
  ushort* woWb  = (ushort*)(ws + 25165824);            //  8.39 MB
  ushort* inter = (ushort*)(ws + 33554432);            // 67.1  MB
  int*    top1  = (int*)   (ws + 100663296);           // 32 KB
  float*  coeff = (float*) (ws + 100696064);           // 128 KB

  cast2_kernel<<<8192, 256, 0, stream>>>(wi_W, wo_W, wiWb, woWb);
  router_kernel<<<N_TOK / 4, 256, 0, stream>>>(x, gate_W, gate_b, lora_A, top1, coeff, xb);
  gemm1_kernel<<<512, 512, 0, stream>>>(
      xb, wiWb, wi_b, top1, (const float4*)coeff, (const float4*)lora_B, inter);
  gemm2_kernel<<<512, 256, 0, stream>>>(inter, woWb, wo_b, out);
}

// Round 7
// 251.456 us; speedup vs baseline: 1.2289x; 1.0815x over previous
//
#include <hip/hip_runtime.h>
#include <hip/hip_bf16.h>
#include <stdint.h>

#define N_TOK 8192
#define DDIM 1024
#define FDIM 4096
#define NEXP 8

typedef __attribute__((ext_vector_type(8))) short short8;
typedef __attribute__((ext_vector_type(4))) float f32x4;

#define SCHED_FENCE __builtin_amdgcn_sched_barrier(0)
#define CFENCE asm volatile("" ::: "memory")
#define HWBAR __builtin_amdgcn_s_barrier()

__device__ __forceinline__ ushort f2bf(float f) {
  uint32_t u = __float_as_uint(f);
  u += 0x7FFF + ((u >> 16) & 1);   // RNE
  return (ushort)(u >> 16);
}

__device__ __forceinline__ void gload16(const void* g, void* l) {
  __builtin_amdgcn_global_load_lds((const __attribute__((address_space(1))) void*)g,
                                   (__attribute__((address_space(3))) void*)l, 16, 0, 0);
}

// ---------- fused cast f32 -> bf16 for both weight matrices ----------
__global__ __launch_bounds__(256) void cast2_kernel(const float* __restrict__ wi,
                                                    const float* __restrict__ wo,
                                                    ushort* __restrict__ wib,
                                                    ushort* __restrict__ wob) {
  const int N1 = FDIM * DDIM / 4;
  int i = blockIdx.x * 256 + threadIdx.x;
  const float* src;
  ushort* dst;
  int j;
  if (i < N1) { src = wi; dst = wib; j = i; }
  else        { src = wo; dst = wob; j = i - N1; }
  float4 v = reinterpret_cast<const float4*>(src)[j];
  ushort4 o;
  o.x = f2bf(v.x); o.y = f2bf(v.y); o.z = f2bf(v.z); o.w = f2bf(v.w);
  reinterpret_cast<ushort4*>(dst)[j] = o;
}

// ---------- router (proven) ----------
__global__ __launch_bounds__(256) void router_kernel(
    const float* __restrict__ x, const float* __restrict__ gW, const float* __restrict__ gb,
    const float* __restrict__ lA, int* __restrict__ top1, float* __restrict__ coeff,
    ushort* __restrict__ xb) {
  const int lane = threadIdx.x & 63;
  const int wid = threadIdx.x >> 6;
  const int tok = blockIdx.x * 4 + wid;
  const float* xp = x + (size_t)tok * DDIM;
  float4 xv[4];
#pragma unroll
  for (int i = 0; i < 4; ++i)
    xv[i] = *reinterpret_cast<const float4*>(xp + i * 256 + lane * 4);
#pragma unroll
  for (int i = 0; i < 4; ++i) {
    ushort4 o;
    o.x = f2bf(xv[i].x); o.y = f2bf(xv[i].y); o.z = f2bf(xv[i].z); o.w = f2bf(xv[i].w);
    *reinterpret_cast<ushort4*>(xb + (size_t)tok * DDIM + i * 256 + lane * 4) = o;
  }
  double lg[NEXP];
#pragma unroll
  for (int e = 0; e < NEXP; ++e) {
    const float* gp = gW + e * DDIM;
    double s = 0.0;
#pragma unroll
    for (int i = 0; i < 4; ++i) {
      float4 g = *reinterpret_cast<const float4*>(gp + i * 256 + lane * 4);
      s += (double)xv[i].x * g.x + (double)xv[i].y * g.y +
           (double)xv[i].z * g.z + (double)xv[i].w * g.w;
    }
    lg[e] = s;
  }
#pragma unroll
  for (int e = 0; e < NEXP; ++e)
    for (int off = 32; off > 0; off >>= 1) lg[e] += __shfl_xor(lg[e], off);
  int best = 0;
  double bv = lg[0] + (double)gb[0];
#pragma unroll
  for (int e = 1; e < NEXP; ++e) {
    double v = lg[e] + (double)gb[e];
    if (v > bv) { bv = v; best = e; }
  }
  float c[4];
#pragma unroll
  for (int r = 0; r < 4; ++r) {
    const float* ap = lA + ((size_t)best * 4 + r) * DDIM;
    float s = 0.f;
#pragma unroll
    for (int i = 0; i < 4; ++i) {
      float4 a = *reinterpret_cast<const float4*>(ap + i * 256 + lane * 4);
      s = fmaf(xv[i].x, a.x, s); s = fmaf(xv[i].y, a.y, s);
      s = fmaf(xv[i].z, a.z, s); s = fmaf(xv[i].w, a.w, s);
    }
    for (int off = 32; off > 0; off >>= 1) s += __shfl_xor(s, off);
    c[r] = s;
  }
  if (lane == 0) {
    top1[tok] = best;
    float4 cc; cc.x = c[0]; cc.y = c[1]; cc.z = c[2]; cc.w = c[3];
    *reinterpret_cast<float4*>(coeff + tok * 4) = cc;
  }
}

// =====================================================================
// GEMM1 (round-2 proven, ~86us): 256x256 tile, BK=32, 8 waves (2Mx4N),
// 4-slot LDS ring, 2-tile lookahead, per-tile vmcnt(4).
// Swizzle = R2 orientation (per-XCD: 4 A-slices + all B ~ 10.4MB).
// =====================================================================
__global__ __launch_bounds__(512, 2) void gemm1_kernel(
    const ushort* __restrict__ A, const ushort* __restrict__ B,
    const float* __restrict__ bias, const int* __restrict__ top1,
    const float4* __restrict__ coeff, const float4* __restrict__ loraB,
    ushort* __restrict__ C) {
  __shared__ __align__(16) ushort lds[65536];     // 128 KiB
  const int tid = threadIdx.x;
  const int lane = tid & 63;
  const int wid = tid >> 6;
  const int wr = wid >> 2, wc = wid & 3;          // 2M x 4N waves

  int bid = blockIdx.x;
  int swz = (bid & 7) * 64 + (bid >> 3);
  const int brow = swz >> 4;                      // 32 m-blocks
  const int bcol = swz & 15;                      // 16 n-blocks

  const int NT = DDIM / 32;                       // 32 k-tiles

  const int rs = tid & 255, ch = tid >> 8;        // ch in {0,1}
  const ushort* gA0 = A + (size_t)(brow * 256 + rs) * DDIM + ch * 8;
  const ushort* gA1 = gA0 + 16;
  const ushort* gB0 = B + (size_t)(bcol * 256 + rs) * DDIM + ch * 8;
  const ushort* gB1 = gB0 + 16;
  ushort* const sdst = lds + tid * 8;

  const int cA = lane >> 4, rlo = lane & 15;
  const int aoff = ((cA << 8) + wr * 128 + rlo) * 8;          // + (h*4+fm)*128
  const int boff = 8192 + ((cA << 8) + wc * 64 + rlo) * 8;    // + fn*128

  f32x4 acc[8][4] = {};

  // prologue: stage tiles 0 (slot0) and 1 (slot1)
  gload16(gA0,      sdst);                 gload16(gA1,      sdst + 4096);
  gload16(gB0,      sdst + 8192);          gload16(gB1,      sdst + 12288);
  gload16(gA0 + 32, sdst + 16384);         gload16(gA1 + 32, sdst + 16384 + 4096);
  gload16(gB0 + 32, sdst + 16384 + 8192);  gload16(gB1 + 32, sdst + 16384 + 12288);
  asm volatile("s_waitcnt vmcnt(4)" ::: "memory");
  SCHED_FENCE; HWBAR; SCHED_FENCE;

#pragma unroll 1
  for (int t = 0; t < NT; ++t) {
    const ushort* sp = lds + (t & 3) * 16384;
    const int t2 = t + 2;
    ushort* s2 = sdst + (t2 & 3) * 16384;
    const int k2 = t2 * 32;
    short8 a0[4], b0[4];
    // ---- phase 0: read A(h=0) + B, stage A of tile t+2 ----
    CFENCE;
#pragma unroll
    for (int fm = 0; fm < 4; ++fm)
      a0[fm] = *reinterpret_cast<const short8*>(sp + aoff + fm * 128);
#pragma unroll
    for (int fn = 0; fn < 4; ++fn)
      b0[fn] = *reinterpret_cast<const short8*>(sp + boff + fn * 128);
    if (t2 < NT) { gload16(gA0 + k2, s2); gload16(gA1 + k2, s2 + 4096); }
    CFENCE; SCHED_FENCE; HWBAR; SCHED_FENCE;
    __builtin_amdgcn_s_setprio(1);
#pragma unroll
    for (int fn = 0; fn < 4; ++fn)
#pragma unroll
      for (int fm = 0; fm < 4; ++fm)
        acc[fm][fn] = __builtin_amdgcn_mfma_f32_16x16x32_bf16(a0[fm], b0[fn], acc[fm][fn], 0, 0, 0);
    __builtin_amdgcn_s_setprio(0);
    SCHED_FENCE; CFENCE; HWBAR; SCHED_FENCE;
    // ---- phase 1: read A(h=1), stage B of tile t+2, tile-end wait ----
    CFENCE;
#pragma unroll
    for (int fm = 0; fm < 4; ++fm)
      a0[fm] = *reinterpret_cast<const short8*>(sp + aoff + 512 + fm * 128);
    if (t2 < NT) { gload16(gB0 + k2, s2 + 8192); gload16(gB1 + k2, s2 + 12288); }
    CFENCE; SCHED_FENCE; HWBAR; SCHED_FENCE;
    __builtin_amdgcn_s_setprio(1);
#pragma unroll
    for (int fn = 0; fn < 4; ++fn)
#pragma unroll
      for (int fm = 0; fm < 4; ++fm)
        acc[4 + fm][fn] = __builtin_amdgcn_mfma_f32_16x16x32_bf16(a0[fm], b0[fn], acc[4 + fm][fn], 0, 0, 0);
    __builtin_amdgcn_s_setprio(0);
    SCHED_FENCE;
    if (t2 < NT) asm volatile("s_waitcnt vmcnt(4)" ::: "memory");
    else         asm volatile("s_waitcnt vmcnt(0)" ::: "memory");
    HWBAR; SCHED_FENCE;
  }

  // ---- epilogue: LDS-staged lora/coeff/top1, fused bias+lora+relu ----
  __syncthreads();
  char* lb = (char*)lds;
  float4* lora_s  = (float4*)lb;             // [8][256] = 32 KB
  float4* coeff_s = (float4*)(lb + 32768);   // [256]
  int*    top1_s  = (int*)  (lb + 36864);    // [256]
#pragma unroll
  for (int i = 0; i < 4; ++i) {
    int idx = tid + i * 512;
    lora_s[idx] = loraB[(size_t)(idx >> 8) * FDIM + bcol * 256 + (idx & 255)];
  }
  if (tid < 256) {
    coeff_s[tid] = coeff[brow * 256 + tid];
    top1_s[tid]  = top1[brow * 256 + tid];
  }
  __syncthreads();

  const int ccb = wc * 64 + (lane & 15);
  float bias4[4];
#pragma unroll
  for (int fn = 0; fn < 4; ++fn) bias4[fn] = bias[bcol * 256 + ccb + fn * 16];
#pragma unroll
  for (int fm = 0; fm < 8; ++fm) {
#pragma unroll
    for (int q = 0; q < 4; ++q) {
      const int tl = wr * 128 + fm * 16 + ((lane >> 4) << 2) + q;
      const int e = top1_s[tl];
      const float4 cf = coeff_s[tl];
      ushort* crow = C + (size_t)(brow * 256 + tl) * FDIM + bcol * 256;
#pragma unroll
      for (int fn = 0; fn < 4; ++fn) {
        const int cc = ccb + fn * 16;
        const float4 l4 = lora_s[e * 256 + cc];
        float v = acc[fm][fn][q] + bias4[fn] +
                  cf.x * l4.x + cf.y * l4.y + cf.z * l4.z + cf.w * l4.w;
        crow[cc] = f2bf(fmaxf(v, 0.f));
      }
    }
  }
}

// =====================================================================
// GEMM2 (round-1 proven regime + zero-conflict LDS): out = inter @ woWb^T + wo_b
// 128x128 tile, BK=32, 256 thr (2x2 waves of 64x64), single-buffer 16KB
// chunk-major LDS, compiler-scheduled __syncthreads, 2 blocks/CU.
// Mapping = R1 natural: bid = m + 64n -> XCD = m%8 (A-slice pinned to XCD,
// B replicated: per-XCD 8 A-slices + 8 B-panels = 16MB, total ~134MB).
// =====================================================================
__global__ __launch_bounds__(256) void gemm2_kernel(
    const ushort* __restrict__ A, const ushort* __restrict__ B,
    const float* __restrict__ bias, float* __restrict__ C) {
  __shared__ __align__(16) ushort lds[8192];     // 16 KB
  const int tid = threadIdx.x;
  const int lane = tid & 63;
  const int wid = tid >> 6;
  const int wr = wid >> 1, wc = wid & 1;

  const int bid = blockIdx.x;                    // nwg = 512 (64 m x 8 n)
  const int brow = bid & 63;                     // m fastest -> XCD = m%8
  const int bcol = bid >> 6;

  const int rs = tid & 127, ch = tid >> 7;
  const ushort* gA = A + (size_t)(brow * 128 + rs) * FDIM + ch * 8;
  const ushort* gB = B + (size_t)(bcol * 128 + rs) * FDIM + ch * 8;
  ushort* const dstA = lds + tid * 8;            // [chunk][row][8]
  ushort* const dstB = lds + 4096 + tid * 8;

  const int g = lane >> 4, rlo = lane & 15;
  const int aoff = g * 1024 + (wr * 64 + rlo) * 8;
  const int boff = 4096 + g * 1024 + (wc * 64 + rlo) * 8;

  f32x4 acc[4][4] = {};

  for (int t = 0; t < FDIM / 32; ++t) {
    const int k0 = t * 32;
    gload16(gA + k0, dstA);  gload16(gA + k0 + 16, dstA + 2048);
    gload16(gB + k0, dstB);  gload16(gB + k0 + 16, dstB + 2048);
    __syncthreads();
    short8 a[4], b[4];
#pragma unroll
    for (int fm = 0; fm < 4; ++fm)
      a[fm] = *reinterpret_cast<const short8*>(lds + aoff + fm * 128);
#pragma unroll
    for (int fn = 0; fn < 4; ++fn)
      b[fn] = *reinterpret_cast<const short8*>(lds + boff + fn * 128);
#pragma unroll
    for (int fn = 0; fn < 4; ++fn)
#pragma unroll
      for (int fm = 0; fm < 4; ++fm)
        acc[fm][fn] = __builtin_amdgcn_mfma_f32_16x16x32_bf16(a[fm], b[fn], acc[fm][fn], 0, 0, 0);
    __syncthreads();
  }

  const int ccb = wc * 64 + (lane & 15);
  float bias4[4];
#pragma unroll
  for (int fn = 0; fn < 4; ++fn) bias4[fn] = bias[bcol * 128 + ccb + fn * 16];
#pragma unroll
  for (int fm = 0; fm < 4; ++fm) {
#pragma unroll
    for (int q = 0; q < 4; ++q) {
      const int tl = wr * 64 + fm * 16 + ((lane >> 4) << 2) + q;
      float* crow = C + (size_t)(brow * 128 + tl) * DDIM + bcol * 128;
#pragma unroll
      for (int fn = 0; fn < 4; ++fn)
        crow[ccb + fn * 16] = acc[fm][fn][q] + bias4[fn];
    }
  }
}

extern "C" void kernel_launch(void* const* d_in, const int* in_sizes, int n_in,
                              void* d_out, int out_size, void* d_ws, size_t ws_size,
                              hipStream_t stream) {
  const float* x      = (const float*)d_in[0];
  const float* gate_W = (const float*)d_in[1];
  const float* gate_b = (const float*)d_in[2];
  const float* wi_W   = (const float*)d_in[3];
  const float* wi_b   = (const float*)d_in[4];
  const float* wo_W   = (const float*)d_in[5];
  const float* wo_b   = (const float*)d_in[6];
  const float* lora_A = (const float*)d_in[7];
  const float* lora_B = (const float*)d_in[8];
  float* out = (float*)d_out;

  char* ws = (char*)d_ws;
  ushort* xb    = (ushort*)(ws);                       // 16.78 MB
  ushort* wiWb  = (ushort*)(ws + 16777216);            //  8.39 MB
  ushort* woWb  = (ushort*)(ws + 25165824);            //  8.39 MB
  ushort* inter = (ushort*)(ws + 33554432);            // 67.1  MB
  int*    top1  = (int*)   (ws + 100663296);           // 32 KB
  float*  coeff = (float*) (ws + 100696064);           // 128 KB

  cast2_kernel<<<8192, 256, 0, stream>>>(wi_W, wo_W, wiWb, woWb);
  router_kernel<<<N_TOK / 4, 256, 0, stream>>>(x, gate_W, gate_b, lora_A, top1, coeff, xb);
  gemm1_kernel<<<512, 512, 0, stream>>>(
      xb, wiWb, wi_b, top1, (const float4*)coeff, (const float4*)lora_B, inter);
  gemm2_kernel<<<512, 256, 0, stream>>>(inter, woWb, wo_b, out);
}

// Round 8
// 206.551 us; speedup vs baseline: 1.4960x; 1.2174x over previous
//
#include <hip/hip_runtime.h>
#include <hip/hip_bf16.h>
#include <stdint.h>

#define N_TOK 8192
#define DDIM 1024
#define FDIM 4096
#define NEXP 8

typedef __attribute__((ext_vector_type(8))) short short8;
typedef __attribute__((ext_vector_type(4))) float f32x4;

#define SCHED_FENCE __builtin_amdgcn_sched_barrier(0)
#define CFENCE asm volatile("" ::: "memory")
#define HWBAR __builtin_amdgcn_s_barrier()

__device__ __forceinline__ ushort f2bf(float f) {
  uint32_t u = __float_as_uint(f);
  u += 0x7FFF + ((u >> 16) & 1);   // RNE
  return (ushort)(u >> 16);
}

__device__ __forceinline__ void gload16(const void* g, void* l) {
  __builtin_amdgcn_global_load_lds((const __attribute__((address_space(1))) void*)g,
                                   (__attribute__((address_space(3))) void*)l, 16, 0, 0);
}

// ---------- fused cast f32 -> bf16 for both weight matrices ----------
__global__ __launch_bounds__(256) void cast2_kernel(const float* __restrict__ wi,
                                                    const float* __restrict__ wo,
                                                    ushort* __restrict__ wib,
                                                    ushort* __restrict__ wob) {
  const int N1 = FDIM * DDIM / 4;
  int i = blockIdx.x * 256 + threadIdx.x;
  const float* src;
  ushort* dst;
  int j;
  if (i < N1) { src = wi; dst = wib; j = i; }
  else        { src = wo; dst = wob; j = i - N1; }
  float4 v = reinterpret_cast<const float4*>(src)[j];
  ushort4 o;
  o.x = f2bf(v.x); o.y = f2bf(v.y); o.z = f2bf(v.z); o.w = f2bf(v.w);
  reinterpret_cast<ushort4*>(dst)[j] = o;
}

// ---------- router (proven) ----------
__global__ __launch_bounds__(256) void router_kernel(
    const float* __restrict__ x, const float* __restrict__ gW, const float* __restrict__ gb,
    const float* __restrict__ lA, int* __restrict__ top1, float* __restrict__ coeff,
    ushort* __restrict__ xb) {
  const int lane = threadIdx.x & 63;
  const int wid = threadIdx.x >> 6;
  const int tok = blockIdx.x * 4 + wid;
  const float* xp = x + (size_t)tok * DDIM;
  float4 xv[4];
#pragma unroll
  for (int i = 0; i < 4; ++i)
    xv[i] = *reinterpret_cast<const float4*>(xp + i * 256 + lane * 4);
#pragma unroll
  for (int i = 0; i < 4; ++i) {
    ushort4 o;
    o.x = f2bf(xv[i].x); o.y = f2bf(xv[i].y); o.z = f2bf(xv[i].z); o.w = f2bf(xv[i].w);
    *reinterpret_cast<ushort4*>(xb + (size_t)tok * DDIM + i * 256 + lane * 4) = o;
  }
  double lg[NEXP];
#pragma unroll
  for (int e = 0; e < NEXP; ++e) {
    const float* gp = gW + e * DDIM;
    double s = 0.0;
#pragma unroll
    for (int i = 0; i < 4; ++i) {
      float4 g = *reinterpret_cast<const float4*>(gp + i * 256 + lane * 4);
      s += (double)xv[i].x * g.x + (double)xv[i].y * g.y +
           (double)xv[i].z * g.z + (double)xv[i].w * g.w;
    }
    lg[e] = s;
  }
#pragma unroll
  for (int e = 0; e < NEXP; ++e)
    for (int off = 32; off > 0; off >>= 1) lg[e] += __shfl_xor(lg[e], off);
  int best = 0;
  double bv = lg[0] + (double)gb[0];
#pragma unroll
  for (int e = 1; e < NEXP; ++e) {
    double v = lg[e] + (double)gb[e];
    if (v > bv) { bv = v; best = e; }
  }
  float c[4];
#pragma unroll
  for (int r = 0; r < 4; ++r) {
    const float* ap = lA + ((size_t)best * 4 + r) * DDIM;
    float s = 0.f;
#pragma unroll
    for (int i = 0; i < 4; ++i) {
      float4 a = *reinterpret_cast<const float4*>(ap + i * 256 + lane * 4);
      s = fmaf(xv[i].x, a.x, s); s = fmaf(xv[i].y, a.y, s);
      s = fmaf(xv[i].z, a.z, s); s = fmaf(xv[i].w, a.w, s);
    }
    for (int off = 32; off > 0; off >>= 1) s += __shfl_xor(s, off);
    c[r] = s;
  }
  if (lane == 0) {
    top1[tok] = best;
    float4 cc; cc.x = c[0]; cc.y = c[1]; cc.z = c[2]; cc.w = c[3];
    *reinterpret_cast<float4*>(coeff + tok * 4) = cc;
  }
}

// =====================================================================
// GEMM1 (round-2/7 proven, ~86-89us): 256x256 tile, BK=32, 8 waves
// (2Mx4N), 4-slot LDS ring, 2-tile lookahead, per-tile vmcnt(4).
// =====================================================================
__global__ __launch_bounds__(512, 2) void gemm1_kernel(
    const ushort* __restrict__ A, const ushort* __restrict__ B,
    const float* __restrict__ bias, const int* __restrict__ top1,
    const float4* __restrict__ coeff, const float4* __restrict__ loraB,
    ushort* __restrict__ C) {
  __shared__ __align__(16) ushort lds[65536];     // 128 KiB
  const int tid = threadIdx.x;
  const int lane = tid & 63;
  const int wid = tid >> 6;
  const int wr = wid >> 2, wc = wid & 3;          // 2M x 4N waves

  int bid = blockIdx.x;
  int swz = (bid & 7) * 64 + (bid >> 3);
  const int brow = swz >> 4;                      // 32 m-blocks
  const int bcol = swz & 15;                      // 16 n-blocks

  const int NT = DDIM / 32;                       // 32 k-tiles

  const int rs = tid & 255, ch = tid >> 8;        // ch in {0,1}
  const ushort* gA0 = A + (size_t)(brow * 256 + rs) * DDIM + ch * 8;
  const ushort* gA1 = gA0 + 16;
  const ushort* gB0 = B + (size_t)(bcol * 256 + rs) * DDIM + ch * 8;
  const ushort* gB1 = gB0 + 16;
  ushort* const sdst = lds + tid * 8;

  const int cA = lane >> 4, rlo = lane & 15;
  const int aoff = ((cA << 8) + wr * 128 + rlo) * 8;          // + (h*4+fm)*128
  const int boff = 8192 + ((cA << 8) + wc * 64 + rlo) * 8;    // + fn*128

  f32x4 acc[8][4] = {};

  // prologue: stage tiles 0 (slot0) and 1 (slot1)
  gload16(gA0,      sdst);                 gload16(gA1,      sdst + 4096);
  gload16(gB0,      sdst + 8192);          gload16(gB1,      sdst + 12288);
  gload16(gA0 + 32, sdst + 16384);         gload16(gA1 + 32, sdst + 16384 + 4096);
  gload16(gB0 + 32, sdst + 16384 + 8192);  gload16(gB1 + 32, sdst + 16384 + 12288);
  asm volatile("s_waitcnt vmcnt(4)" ::: "memory");
  SCHED_FENCE; HWBAR; SCHED_FENCE;

#pragma unroll 1
  for (int t = 0; t < NT; ++t) {
    const ushort* sp = lds + (t & 3) * 16384;
    const int t2 = t + 2;
    ushort* s2 = sdst + (t2 & 3) * 16384;
    const int k2 = t2 * 32;
    short8 a0[4], b0[4];
    // ---- phase 0: read A(h=0) + B, stage A of tile t+2 ----
    CFENCE;
#pragma unroll
    for (int fm = 0; fm < 4; ++fm)
      a0[fm] = *reinterpret_cast<const short8*>(sp + aoff + fm * 128);
#pragma unroll
    for (int fn = 0; fn < 4; ++fn)
      b0[fn] = *reinterpret_cast<const short8*>(sp + boff + fn * 128);
    if (t2 < NT) { gload16(gA0 + k2, s2); gload16(gA1 + k2, s2 + 4096); }
    CFENCE; SCHED_FENCE; HWBAR; SCHED_FENCE;
    __builtin_amdgcn_s_setprio(1);
#pragma unroll
    for (int fn = 0; fn < 4; ++fn)
#pragma unroll
      for (int fm = 0; fm < 4; ++fm)
        acc[fm][fn] = __builtin_amdgcn_mfma_f32_16x16x32_bf16(a0[fm], b0[fn], acc[fm][fn], 0, 0, 0);
    __builtin_amdgcn_s_setprio(0);
    SCHED_FENCE; CFENCE; HWBAR; SCHED_FENCE;
    // ---- phase 1: read A(h=1), stage B of tile t+2, tile-end wait ----
    CFENCE;
#pragma unroll
    for (int fm = 0; fm < 4; ++fm)
      a0[fm] = *reinterpret_cast<const short8*>(sp + aoff + 512 + fm * 128);
    if (t2 < NT) { gload16(gB0 + k2, s2 + 8192); gload16(gB1 + k2, s2 + 12288); }
    CFENCE; SCHED_FENCE; HWBAR; SCHED_FENCE;
    __builtin_amdgcn_s_setprio(1);
#pragma unroll
    for (int fn = 0; fn < 4; ++fn)
#pragma unroll
      for (int fm = 0; fm < 4; ++fm)
        acc[4 + fm][fn] = __builtin_amdgcn_mfma_f32_16x16x32_bf16(a0[fm], b0[fn], acc[4 + fm][fn], 0, 0, 0);
    __builtin_amdgcn_s_setprio(0);
    SCHED_FENCE;
    if (t2 < NT) asm volatile("s_waitcnt vmcnt(4)" ::: "memory");
    else         asm volatile("s_waitcnt vmcnt(0)" ::: "memory");
    HWBAR; SCHED_FENCE;
  }

  // ---- epilogue: LDS-staged lora/coeff/top1, fused bias+lora+relu ----
  __syncthreads();
  char* lb = (char*)lds;
  float4* lora_s  = (float4*)lb;             // [8][256] = 32 KB
  float4* coeff_s = (float4*)(lb + 32768);   // [256]
  int*    top1_s  = (int*)  (lb + 36864);    // [256]
#pragma unroll
  for (int i = 0; i < 4; ++i) {
    int idx = tid + i * 512;
    lora_s[idx] = loraB[(size_t)(idx >> 8) * FDIM + bcol * 256 + (idx & 255)];
  }
  if (tid < 256) {
    coeff_s[tid] = coeff[brow * 256 + tid];
    top1_s[tid]  = top1[brow * 256 + tid];
  }
  __syncthreads();

  const int ccb = wc * 64 + (lane & 15);
  float bias4[4];
#pragma unroll
  for (int fn = 0; fn < 4; ++fn) bias4[fn] = bias[bcol * 256 + ccb + fn * 16];
#pragma unroll
  for (int fm = 0; fm < 8; ++fm) {
#pragma unroll
    for (int q = 0; q < 4; ++q) {
      const int tl = wr * 128 + fm * 16 + ((lane >> 4) << 2) + q;
      const int e = top1_s[tl];
      const float4 cf = coeff_s[tl];
      ushort* crow = C + (size_t)(brow * 256 + tl) * FDIM + bcol * 256;
#pragma unroll
      for (int fn = 0; fn < 4; ++fn) {
        const int cc = ccb + fn * 16;
        const float4 l4 = lora_s[e * 256 + cc];
        float v = acc[fm][fn][q] + bias4[fn] +
                  cf.x * l4.x + cf.y * l4.y + cf.z * l4.z + cf.w * l4.w;
        crow[cc] = f2bf(fmaxf(v, 0.f));
      }
    }
  }
}

// =====================================================================
// GEMM2: EXACT round-1 kernel (measured-by-subtraction ~72-77us).
// 128x128 tile, BK=32, 256 thr, row-major LDS (known ~8M bank conflicts
// — empirically NOT binding), compiler-scheduled __syncthreads.
// =====================================================================
__global__ __launch_bounds__(256) void gemm2_kernel(
    const ushort* __restrict__ A, const ushort* __restrict__ B,
    const float* __restrict__ bias, float* __restrict__ C) {
  __shared__ __align__(16) ushort lA[128 * 32];
  __shared__ __align__(16) ushort lB[128 * 32];
  const int tid = threadIdx.x;
  const int lane = tid & 63;
  const int wid = tid >> 6;
  const int wr = wid >> 1, wc = wid & 1;
  const int brow = blockIdx.x, bcol = blockIdx.y;

  f32x4 acc[4][4] = {};

  const int srow = tid >> 2;
  const int scol = (tid & 3) * 8;
  const ushort* gA0 = A + (size_t)(brow * 128 + srow) * FDIM + scol;
  const ushort* gA1 = A + (size_t)(brow * 128 + 64 + srow) * FDIM + scol;
  const ushort* gB0 = B + (size_t)(bcol * 128 + srow) * FDIM + scol;
  const ushort* gB1 = B + (size_t)(bcol * 128 + 64 + srow) * FDIM + scol;
  ushort* lA0 = lA + tid * 8;
  ushort* lA1 = lA + 2048 + tid * 8;
  ushort* lB0 = lB + tid * 8;
  ushort* lB1 = lB + 2048 + tid * 8;

  const int offA = (wr * 64 + (lane & 15)) * 32 + (lane >> 4) * 8;
  const int offB = (wc * 64 + (lane & 15)) * 32 + (lane >> 4) * 8;

  for (int k0 = 0; k0 < FDIM; k0 += 32) {
    gload16(gA0 + k0, lA0);
    gload16(gA1 + k0, lA1);
    gload16(gB0 + k0, lB0);
    gload16(gB1 + k0, lB1);
    __syncthreads();
    short8 af[4], bf[4];
#pragma unroll
    for (int m = 0; m < 4; ++m)
      af[m] = *reinterpret_cast<const short8*>(lA + offA + m * 16 * 32);
#pragma unroll
    for (int n = 0; n < 4; ++n)
      bf[n] = *reinterpret_cast<const short8*>(lB + offB + n * 16 * 32);
#pragma unroll
    for (int n = 0; n < 4; ++n)
#pragma unroll
      for (int m = 0; m < 4; ++m)
        acc[m][n] = __builtin_amdgcn_mfma_f32_16x16x32_bf16(af[m], bf[n], acc[m][n], 0, 0, 0);
    __syncthreads();
  }

  const int dbase = bcol * 128 + wc * 64 + (lane & 15);
  const int tokbase = brow * 128 + wr * 64 + ((lane >> 4) << 2);
  float bias4[4];
#pragma unroll
  for (int n = 0; n < 4; ++n) bias4[n] = bias[dbase + n * 16];
#pragma unroll
  for (int m = 0; m < 4; ++m) {
#pragma unroll
    for (int q = 0; q < 4; ++q) {
      const int tok = tokbase + m * 16 + q;
#pragma unroll
      for (int n = 0; n < 4; ++n)
        C[(size_t)tok * DDIM + dbase + n * 16] = acc[m][n][q] + bias4[n];
    }
  }
}

extern "C" void kernel_launch(void* const* d_in, const int* in_sizes, int n_in,
                              void* d_out, int out_size, void* d_ws, size_t ws_size,
                              hipStream_t stream) {
  const float* x      = (const float*)d_in[0];
  const float* gate_W = (const float*)d_in[1];
  const float* gate_b = (const float*)d_in[2];
  const float* wi_W   = (const float*)d_in[3];
  const float* wi_b   = (const float*)d_in[4];
  const float* wo_W   = (const float*)d_in[5];
  const float* wo_b   = (const float*)d_in[6];
  const float* lora_A = (const float*)d_in[7];
  const float* lora_B = (const float*)d_in[8];
  float* out = (float*)d_out;

  char* ws = (char*)d_ws;
  ushort* xb    = (ushort*)(ws);                       // 16.78 MB
  ushort* wiWb  = (ushort*)(ws + 16777216);            //  8.39 MB
  ushort* woWb  = (ushort*)(ws + 25165824);            //  8.39 MB
  ushort* inter = (ushort*)(ws + 33554432);            // 67.1  MB
  int*    top1  = (int*)   (ws + 100663296);           // 32 KB
  float*  coeff = (float*) (ws + 100696064);           // 128 KB

  cast2_kernel<<<8192, 256, 0, stream>>>(wi_W, wo_W, wiWb, woWb);
  router_kernel<<<N_TOK / 4, 256, 0, stream>>>(x, gate_W, gate_b, lora_A, top1, coeff, xb);
  gemm1_kernel<<<512, 512, 0, stream>>>(
      xb, wiWb, wi_b, top1, (const float4*)coeff, (const float4*)lora_B, inter);
  gemm2_kernel<<<dim3(N_TOK / 128, DDIM / 128), 256, 0, stream>>>(inter, woWb, wo_b, out);
}